// Round 5
// baseline (474.585 us; speedup 1.0000x reference)
//
#include <hip/hip_runtime.h>

// J_row: 4096x4096 f32, J_col: 4096x4096 f32
// out[4][4096][4096] f32; group g = J_row[:, g*1024:(g+1)*1024] @ J_col[:, same]^T
// group 3: cols 3584:4096 scaled by 0.5 (folded into B during convert).
//
// Workspace holds a PACKED bf16 copy of both matrices:
//   P[mat][kt][m][slot], slot = kchunk ^ ((m>>1)&3)   (bank swizzle baked in)
// so each K-tile's 256x32 panel is a contiguous 16 KB span -> staging
// global_load_lds reads are fully contiguous.
//
// GEMM: m201-style 8-phase schedule over pairs of K-tiles: per phase
// {ds_read quadrant frags, 1 stage gload, barrier, lgkmcnt(0),
// setprio(1) 8xMFMA setprio(0), barrier}; counted vmcnt(8) only at
// phases 4/8 (tail peels 8->4->0).

typedef unsigned short ushort_t;
typedef __bf16 bf16x8 __attribute__((ext_vector_type(8)));
typedef float floatx4 __attribute__((ext_vector_type(4)));
typedef unsigned short ushortx8 __attribute__((ext_vector_type(8)));

#define PDIM 4096
#define BM 256
#define BN 256
#define BK 32
#define NBUF 4             // LDS ring depth (prefetch distance 3)
#define BUFE 16384         // ushorts per ring slot: A 8192 + B 8192 = 32 KB
#define NT 128             // K tiles
#define GT 32              // K tiles per group
#define KTSZ (PDIM * BK)   // ushorts per packed k-tile plane (131072)

__device__ __forceinline__ unsigned short f2bf_rne(float f) {
  union { float f; unsigned u; } v; v.f = f;
  unsigned u = v.u;
  unsigned r = u + 0x7FFFu + ((u >> 16) & 1u);
  return (unsigned short)(r >> 16);
}

// Convert + pack. Block = 256 threads over a [64 rows x 32 cols] tile of one
// (mat, kt, mb). Thread (r = tid>>2, s = tid&3): reads 8 f32 (32B, row-major,
// lines fully used), writes 16B at packed slot s^((row>>1)&3) -> each wave's
// 64 stores cover a contiguous 1 KB of the packed plane.
__global__ void convert_pack(const float* __restrict__ srcA,
                             const float* __restrict__ srcB,
                             ushort_t* __restrict__ dst) {
  const int mat = blockIdx.y;
  const float* src = mat ? srcB : srcA;
  const int kt = blockIdx.x & 127;
  const int mb = blockIdx.x >> 7;
  const int r = threadIdx.x >> 2;
  const int s = threadIdx.x & 3;
  const int row = mb * 64 + r;
  const float sc = (mat && kt >= 112) ? 0.5f : 1.0f;   // cols>=3584

  const float* p = src + (size_t)row * PDIM + kt * 32 + s * 8;
  float4 x = *(const float4*)p;
  float4 y = *(const float4*)(p + 4);
  ushortx8 o;
  o[0] = f2bf_rne(x.x * sc); o[1] = f2bf_rne(x.y * sc);
  o[2] = f2bf_rne(x.z * sc); o[3] = f2bf_rne(x.w * sc);
  o[4] = f2bf_rne(y.x * sc); o[5] = f2bf_rne(y.y * sc);
  o[6] = f2bf_rne(y.z * sc); o[7] = f2bf_rne(y.w * sc);

  const int slot = s ^ ((row >> 1) & 3);
  ushort_t* q = dst + (size_t)mat * PDIM * PDIM + (size_t)kt * KTSZ +
                row * 32 + slot * 8;
  *(ushortx8*)q = o;
}

__device__ __forceinline__ void async_copy16(const ushort_t* g, ushort_t* l) {
  __builtin_amdgcn_global_load_lds(
      (const __attribute__((address_space(1))) unsigned int*)(g),
      (__attribute__((address_space(3))) unsigned int*)(l),
      16, 0, 0);
}

// One phase: optionally load 4 A-frags, always load 2 B-frags, issue one
// staging chunk, then barrier / lgkm-drain / prio-wrapped 8 MFMAs.
// Caller appends the phase-closing barrier (optionally preceded by a
// counted vmcnt wait at tile boundaries).
#define PHASE(LB, QA, QB, ST, SS, LOADA)                                     \
  do {                                                                       \
    if (LOADA) {                                                             \
      _Pragma("unroll")                                                      \
      for (int i = 0; i < 4; ++i)                                            \
        af[i] = *(const bf16x8*)((LB) + a_off[(QA) * 4 + i]);                \
    }                                                                        \
    _Pragma("unroll")                                                        \
    for (int j = 0; j < 2; ++j)                                              \
      bfr[j] = *(const bf16x8*)((LB) + b_off[(QB) * 2 + j]);                 \
    stage1((ST), (SS));                                                      \
    __builtin_amdgcn_s_barrier();                                            \
    asm volatile("s_waitcnt lgkmcnt(0)" ::: "memory");                       \
    __builtin_amdgcn_s_setprio(1);                                           \
    _Pragma("unroll")                                                        \
    for (int i = 0; i < 4; ++i)                                              \
      _Pragma("unroll")                                                      \
      for (int j = 0; j < 2; ++j)                                            \
        acc[(QA) * 4 + i][(QB) * 2 + j] =                                    \
            __builtin_amdgcn_mfma_f32_16x16x32_bf16(                         \
                af[i], bfr[j], acc[(QA) * 4 + i][(QB) * 2 + j], 0, 0, 0);    \
    __builtin_amdgcn_s_setprio(0);                                           \
  } while (0)

__global__ __launch_bounds__(512, 2) void gemm_grouped(
    const ushort_t* __restrict__ P, float* __restrict__ out) {
  __shared__ ushort_t lds[NBUF * BUFE];   // 128 KB

  const int tid = threadIdx.x;
  const int wave = tid >> 6;
  const int lane = tid & 63;
  const int m16 = lane & 15;
  const int quad = lane >> 4;
  const int wm = wave >> 2;     // 0..1
  const int wn = wave & 3;      // 0..3

  // XCD-aware swizzle: 256 blocks -> each XCD owns a 4x8 tile chunk.
  const int bid = blockIdx.x;
  const int xcd = bid & 7;
  const int loc = bid >> 3;                        // 0..31
  const int tm = (xcd >> 1) * 4 + (loc >> 3);      // 0..15
  const int tn = (xcd & 1) * 8 + (loc & 7);        // 0..15
  const int row0 = tm * BM;
  const int col0 = tn * BN;

  // Staging: 32 contiguous 1KB chunks per K-tile (A: 16, B: 16), 4 per wave,
  // one chunk issued per phase. LDS dest is wave-uniform + lane*16.
  unsigned goff[4];
  int lbase[4];
#pragma unroll
  for (int s = 0; s < 4; ++s) {
    int ch = wave * 4 + s;       // 0..31
    int isB = ch >> 4;
    int chloc = ch & 15;
    goff[s] = (unsigned)isB * (unsigned)(PDIM * PDIM) +
              (unsigned)((isB ? col0 : row0) * 32 + chloc * 512 + lane * 8);
    lbase[s] = isB * 8192 + chloc * 512;
  }

  // Fragment LDS offsets (ushorts) within one ring slot.
  // Packed layout: row-major [m][32] with k-chunk at slot quad^((m>>1)&3).
  // Full-wave ds_read_b128 covers every bank 8x -> conflict-free (measured 0).
  int a_off[8], b_off[4];
  const int ksl = (quad ^ ((m16 >> 1) & 3)) * 8;
#pragma unroll
  for (int i = 0; i < 8; ++i)
    a_off[i] = (wm * 128 + i * 16 + m16) * 32 + ksl;
#pragma unroll
  for (int j = 0; j < 4; ++j)
    b_off[j] = 8192 + (wn * 64 + j * 16 + m16) * 32 + ksl;

  const int orow0 = row0 + wm * 128 + quad * 4;
  const int ocol0 = col0 + wn * 64 + m16;

  floatx4 acc[8][4];
#pragma unroll
  for (int i = 0; i < 8; ++i)
#pragma unroll
    for (int j = 0; j < 4; ++j)
      acc[i][j] = (floatx4){0.f, 0.f, 0.f, 0.f};

  auto stage1 = [&](int t, int s) {
    if (t < NT)
      async_copy16(P + (size_t)t * KTSZ + goff[s],
                   &lds[(t & (NBUF - 1)) * BUFE + lbase[s]]);
  };
  auto stage_all = [&](int t) {
#pragma unroll
    for (int s = 0; s < 4; ++s)
      async_copy16(P + (size_t)t * KTSZ + goff[s],
                   &lds[(t & (NBUF - 1)) * BUFE + lbase[s]]);
  };

  // Prologue: fill 3 deep (12 own loads); vmcnt(8) retires tile 0; barrier
  // extends to all waves.
  stage_all(0); stage_all(1); stage_all(2);
  asm volatile("s_waitcnt vmcnt(8)" ::: "memory");
  __builtin_amdgcn_s_barrier();

  for (int tp = 0; tp < NT / 2; ++tp) {
    const int t0 = tp * 2;
    const ushort_t* lb0 = &lds[(t0 & (NBUF - 1)) * BUFE];
    const ushort_t* lb1 = &lds[((t0 + 1) & (NBUF - 1)) * BUFE];
    bf16x8 af[4], bfr[2];

    // ---- tile t0: phases 1-4 (stage chunks of t0+3) ----
    PHASE(lb0, 0, 0, t0 + 3, 0, true);
    __builtin_amdgcn_s_barrier();
    PHASE(lb0, 0, 1, t0 + 3, 1, false);
    __builtin_amdgcn_s_barrier();
    PHASE(lb0, 1, 0, t0 + 3, 2, true);
    __builtin_amdgcn_s_barrier();
    PHASE(lb0, 1, 1, t0 + 3, 3, false);
    // W1: own outstanding (oldest first) = t0+1, t0+2, t0+3 (4 each, as
    // issued); retire t0+1 before its frags are read in phases 5-8.
    if (tp <= 62) asm volatile("s_waitcnt vmcnt(8)" ::: "memory");
    else          asm volatile("s_waitcnt vmcnt(0)" ::: "memory");
    __builtin_amdgcn_s_barrier();

    // ---- tile t0+1: phases 5-8 (stage chunks of t0+4) ----
    PHASE(lb1, 0, 0, t0 + 4, 0, true);
    __builtin_amdgcn_s_barrier();
    PHASE(lb1, 0, 1, t0 + 4, 1, false);
    __builtin_amdgcn_s_barrier();
    PHASE(lb1, 1, 0, t0 + 4, 2, true);
    __builtin_amdgcn_s_barrier();
    PHASE(lb1, 1, 1, t0 + 4, 3, false);
    // W2: outstanding = t0+2, t0+3, t0+4; retire t0+2 for the next pair.
    if (tp <= 61)      asm volatile("s_waitcnt vmcnt(8)" ::: "memory");
    else if (tp == 62) asm volatile("s_waitcnt vmcnt(4)" ::: "memory");
    else               asm volatile("s_waitcnt vmcnt(0)" ::: "memory");
    __builtin_amdgcn_s_barrier();

    if (((t0 + 2) & (GT - 1)) == 0) {
      // Flush group g; C/D layout: col = lane&15, row = quad*4 + v.
      const int g = (t0 + 1) >> 5;
      float* outp = out + (size_t)g * PDIM * PDIM;
#pragma unroll
      for (int i = 0; i < 8; ++i)
#pragma unroll
        for (int j = 0; j < 4; ++j) {
#pragma unroll
          for (int v = 0; v < 4; ++v)
            outp[(size_t)(orow0 + i * 16 + v) * PDIM + (ocol0 + j * 16)] =
                acc[i][j][v];
          acc[i][j] = (floatx4){0.f, 0.f, 0.f, 0.f};
        }
    }
  }
}

extern "C" void kernel_launch(void* const* d_in, const int* in_sizes, int n_in,
                              void* d_out, int out_size, void* d_ws, size_t ws_size,
                              hipStream_t stream) {
  const float* J_row = (const float*)d_in[0];
  const float* J_col = (const float*)d_in[1];
  float* out = (float*)d_out;

  ushort_t* P = (ushort_t*)d_ws;   // 64 MB packed bf16 (A then B)

  dim3 cgrid(128 * 64, 2);         // (kt, mb) x matrix
  convert_pack<<<cgrid, 256, 0, stream>>>(J_row, J_col, P);

  gemm_grouped<<<dim3(256), 512, 0, stream>>>(P, out);
}